// Round 4
// baseline (190.553 us; speedup 1.0000x reference)
//
#include <hip/hip_runtime.h>
#include <hip/hip_bf16.h>

#define N_NODES 50000
#define N_EDGES 800000
#define BM 64
#define NBUCK 196            // buckets of 256 nodes: d >> 8
#define CAP 8192             // per-bucket capacity (mean ~4096 real + <=1792 pad)
#define CHUNK 2048           // edges per block in bucket pass
#define NB_BUCKET_BLOCKS ((N_EDGES + CHUNK - 1) / CHUNK)   // 391
#define SWZ_BLOCKS 192                                     // 49152 halves
#define SWZ_G 32768          // W_gat offset in swz
#define BFT 1024             // k_bfill threads
#define GBLK ((N_NODES + BM - 1) / BM)                     // 782

typedef _Float16 half4v __attribute__((ext_vector_type(4)));
typedef _Float16 half8 __attribute__((ext_vector_type(8)));
typedef float    float4v __attribute__((ext_vector_type(4)));

__device__ __forceinline__ float elu_f(float v) {
    return (v > 0.f) ? v : (__expf(v) - 1.f);
}

// pack two fp32 -> packed bf16x2 (RNE)
__device__ __forceinline__ unsigned f2bf2(float a, float b) {
    unsigned ua = __float_as_uint(a), ub = __float_as_uint(b);
    ua = (ua + 0x7FFFu + ((ua >> 16) & 1u)) >> 16;
    ub = (ub + 0x7FFFu + ((ub >> 16) & 1u)) >> 16;
    return ua | (ub << 16);
}
__device__ __forceinline__ float2 bf2f2(unsigned u) {
    float2 f;
    f.x = __uint_as_float(u << 16);
    f.y = __uint_as_float(u & 0xFFFF0000u);
    return f;
}

// ---------------- pre-pass: weight swizzle + {detect, bcursor zero} ------
// swz layout: [We 0..8192) N=64 | [Wd 8192..16384) N=128 | [Wo 16384..32768)
// N=128 | [Wg 32768..49152) N=128.
__global__ __launch_bounds__(256) void k_pre(const void* __restrict__ e_raw,
        int* __restrict__ flag,
        const float* __restrict__ We, const float* __restrict__ Wd,
        const float* __restrict__ Wo, const float* __restrict__ Wg,
        _Float16* __restrict__ swz, int* __restrict__ bcursor) {
    const int b = blockIdx.x;
    const int tid = threadIdx.x;
    if (b >= SWZ_BLOCKS) {
        __shared__ int nz;
        if (tid == 0) nz = 0;
        bcursor[tid] = 0;
        __syncthreads();
        int cnt = 0;
        const unsigned* er = (const unsigned*)e_raw;
        for (int i = tid; i < 2048; i += 256)
            if (er[2 * i + 1] != 0u) cnt = 1;
        if (cnt) atomicOr(&nz, 1);
        __syncthreads();
        if (tid == 0) *flag = (nz == 0) ? 1 : 0;   // 1 == int64 layout
        return;
    }
    int t = b * 256 + tid;
    const float* W; int base, N;
    if (t < 8192)       { W = We; base = 0;     N = 64;  }
    else if (t < 16384) { W = Wd; base = 8192;  N = 128; }
    else if (t < 32768) { W = Wo; base = 16384; N = 128; }
    else                { W = Wg; base = SWZ_G; N = 128; }
    int loc = t - base;
    int nnt = N >> 4;
    int frag = loc >> 9, r = loc & 511, lane = r >> 3, j = r & 7;
    int kc = frag / nnt, nt = frag - kc * nnt;
    int k = kc * 32 + ((lane >> 4) << 3) + j;
    int n = nt * 16 + (lane & 15);
    swz[t] = (_Float16)W[k * N + n];
}

// ---------------- fused K1: bucket blocks [0,391) + gat_lin blocks -------
__global__ __launch_bounds__(256) void k_gatlin_bucket(
        const float* __restrict__ x, const _Float16* __restrict__ swz,
        const float* __restrict__ att_s, const float* __restrict__ att_d,
        unsigned* __restrict__ h_bf, float* __restrict__ a_src,
        float* __restrict__ a_dst,
        const void* __restrict__ e_raw, const int* __restrict__ flag,
        int* __restrict__ bcursor, uint2* __restrict__ ebuck) {
    __shared__ __align__(16) char smem[50176];
    const int tid = threadIdx.x;

    if (blockIdx.x < NB_BUCKET_BLOCKS) {
        // ---- bucket body: single-pass fixed-cap bucket sort ----
        int* lh    = (int*)smem;
        int* gbase = (int*)(smem + 1024);
        int* lcur  = (int*)(smem + 2048);
        const int base = blockIdx.x * CHUNK;
        const int is64 = *flag;
        const long long* e64 = (const long long*)e_raw;
        const int* e32 = (const int*)e_raw;

        lh[tid] = 0;
        __syncthreads();
#pragma unroll 4
        for (int j = 0; j < CHUNK / 256; j++) {
            int e = base + j * 256 + tid;
            if (e < N_EDGES) {
                int d = is64 ? (int)e64[N_EDGES + e] : e32[N_EDGES + e];
                atomicAdd(&lh[d >> 8], 1);
            }
        }
        __syncthreads();
        if (lh[tid]) gbase[tid] = atomicAdd(&bcursor[tid], lh[tid]);
        lcur[tid] = 0;
        __syncthreads();
#pragma unroll 4
        for (int j = 0; j < CHUNK / 256; j++) {
            int e = base + j * 256 + tid;
            if (e < N_EDGES) {
                int sN, d;
                if (is64) { sN = (int)e64[e]; d = (int)e64[N_EDGES + e]; }
                else      { sN = e32[e];      d = e32[N_EDGES + e]; }
                int bb = d >> 8;
                int idx = gbase[bb] + atomicAdd(&lcur[bb], 1);
                if (idx < CAP) {
                    uint2 pr; pr.x = (unsigned)sN; pr.y = (unsigned)d;
                    ebuck[bb * CAP + idx] = pr;
                }
            }
        }
        return;
    }

    // ---- gat_lin body: h(bf16) = x @ W_gat via MFMA; att head dots ----
    _Float16* sx = (_Float16*)smem;          // 64*128 f16 = 16 KB
    float*    sh = (float*)(smem + 16384);   // 64*132 f32 = 33.8 KB (pad 132)
    const int m0 = (blockIdx.x - NB_BUCKET_BLOCKS) * 64;

#pragma unroll
    for (int i = 0; i < 8; i++) {
        int idx = tid + i * 256;        // 2048 float4 slots (64 x 32)
        int r = idx >> 5, c4 = idx & 31;
        int row = m0 + r; if (row >= N_NODES) row = N_NODES - 1;
        float4 v = ((const float4*)(x + (size_t)row * 128))[c4];
        half4v h;
        h[0] = (_Float16)v.x; h[1] = (_Float16)v.y;
        h[2] = (_Float16)v.z; h[3] = (_Float16)v.w;
        *(half4v*)&sx[r * 128 + c4 * 4] = h;
    }
    __syncthreads();

    const int wave = tid >> 6, lane = tid & 63;
    const int lm = lane & 15, lq = lane >> 4;
    const int wrow = wave * 16;

    {
        float4v acc[8];
#pragma unroll
        for (int nt = 0; nt < 8; nt++) acc[nt] = (float4v){0.f, 0.f, 0.f, 0.f};
#pragma unroll
        for (int kc = 0; kc < 4; kc++) {
            half8 a = *(const half8*)&sx[(wrow + lm) * 128 + kc * 32 + lq * 8];
#pragma unroll
            for (int nt = 0; nt < 8; nt++) {
                half8 b = *(const half8*)&swz[SWZ_G + (kc * 8 + nt) * 512 + lane * 8];
                acc[nt] = __builtin_amdgcn_mfma_f32_16x16x32_f16(a, b, acc[nt], 0, 0, 0);
            }
        }
        // C/D layout: col = nt*16 + lm, row = lq*4 + r
#pragma unroll
        for (int nt = 0; nt < 8; nt++)
#pragma unroll
            for (int r = 0; r < 4; r++)
                sh[(wrow + lq * 4 + r) * 132 + nt * 16 + lm] = acc[nt][r];
    }
    __syncthreads();

    // epilogue: pack bf16 h + attention dots (8 rows x 4 cols per thread)
    const int c0 = (tid & 31) * 4;
    const int r0 = (tid >> 5) * 8;
    float4 as4 = *(const float4*)&att_s[c0];
    float4 ad4 = *(const float4*)&att_d[c0];
    const int head = c0 >> 5;

#pragma unroll
    for (int r = 0; r < 8; r++) {
        int row = m0 + r0 + r;
        bool ok = row < N_NODES;
        float4 hv = *(const float4*)&sh[(r0 + r) * 132 + c0];
        if (ok) {
            uint2 p;
            p.x = f2bf2(hv.x, hv.y);
            p.y = f2bf2(hv.z, hv.w);
            *(uint2*)&h_bf[(size_t)row * 64 + (c0 >> 1)] = p;
        }
        float vs = hv.x * as4.x + hv.y * as4.y + hv.z * as4.z + hv.w * as4.w;
        float vd = hv.x * ad4.x + hv.y * ad4.y + hv.z * ad4.z + hv.w * ad4.w;
#pragma unroll
        for (int o = 4; o >= 1; o >>= 1) {
            vs += __shfl_down(vs, o, 8);
            vd += __shfl_down(vd, o, 8);
        }
        if (ok && (tid & 7) == 0) {
            a_src[row * 4 + head] = vs;
            a_dst[row * 4 + head] = vd;
        }
    }
}

// per-bucket fine sort -> nodeoff(start, padded_len) + csr_src.
// Segments padded to multiples of 8 with sentinel -1 (no gather tail).
__global__ __launch_bounds__(BFT) void k_bfill(const uint2* __restrict__ ebuck,
        const int* __restrict__ bcursor, int2* __restrict__ nodeoff,
        int* __restrict__ csr_src) {
    __shared__ int lh[256];
    __shared__ int lexc[256];
    __shared__ int lcur[256];
    const int tid = threadIdx.x;
    const int b = blockIdx.x;
    const int lo = b * CAP;
    int cnt = bcursor[b]; if (cnt > CAP) cnt = CAP;
    const int hi = lo + cnt;
    const int n0 = b << 8;

    if (tid < 256) { lh[tid] = 0; lcur[tid] = 0; }
    __syncthreads();
    for (int i = lo + tid; i < hi; i += BFT)
        atomicAdd(&lh[ebuck[i].y & 255], 1);
    __syncthreads();

    int v = 0, p = 0;
    if (tid < 256) {
        v = lh[tid];
        p = (v + 7) & ~7;       // padded length
        lexc[tid] = p;
    }
    __syncthreads();
    for (int o = 1; o < 256; o <<= 1) {
        int u = (tid < 256 && tid >= o) ? lexc[tid - o] : 0;
        __syncthreads();
        if (tid < 256) lexc[tid] += u;
        __syncthreads();
    }
    if (tid < 256) {
        int s = lexc[tid] - p;   // exclusive padded start
        lexc[tid] = s;
        int node = n0 + tid;
        if (node < N_NODES) {
            int2 no;
            no.x = lo + s;
            int maxlen = CAP - s; if (maxlen < 0) maxlen = 0;
            no.y = p <= maxlen ? p : (maxlen & ~7);   // defensive clamp
            nodeoff[node] = no;
        }
    }
    __syncthreads();

    for (int i = lo + tid; i < hi; i += BFT) {
        uint2 pr = ebuck[i];
        int li = (int)(pr.y & 255);
        int pos = atomicAdd(&lcur[li], 1);
        int dst = lexc[li] + pos;
        if (dst < CAP) csr_src[lo + dst] = (int)pr.x;   // clamp: bucket-local
    }
    // sentinel pad fill (disjoint slots from the scatter above)
    if (tid < 256) {
        int base = lexc[tid];
        for (int j = v; j < p && base + j < CAP; j++) csr_src[lo + base + j] = -1;
    }
}

// ---------------- fused K3+K4: gather -> LDS -> 3-layer MFMA MLP ---------
// 1024 threads = 16 waves per 64-node tile. Gather: wave w owns nodes
// m0+4w..+3, writes x1 = elu(agg+b_gat) as f16 straight into sx (no agg
// round-trip through global). MLP: wave (wr=w>>2, wn=w&3) does row-slab
// wr (16 rows) x N-group wn.
__global__ __launch_bounds__(1024) void k_gather_mlp(
        const int2* __restrict__ nodeoff, const int* __restrict__ csr_src,
        const float* __restrict__ a_src, const float* __restrict__ a_dst,
        const unsigned* __restrict__ h_bf, const float* __restrict__ b_gat,
        const _Float16* __restrict__ swz, const float* __restrict__ b_enc,
        const float* __restrict__ b_dec, const float* __restrict__ b_out,
        float* __restrict__ out) {
    __shared__ _Float16 sx[64 * 128];    // 16 KB: X1, then X2
    __shared__ _Float16 se[64 * 64];     // 8 KB: E
    const int tid = threadIdx.x;
    const int wave = tid >> 6, lane = tid & 63;
    const int m0 = blockIdx.x * 64;
    const int half = lane >> 5;
    const int l32 = lane & 31;
    const int hd = l32 >> 3;
    const float4 bg = ((const float4*)b_gat)[l32];

    // ---- gather phase: 4 nodes per wave ----
    for (int k = 0; k < 4; k++) {
        const int r = wave * 4 + k;
        const int d = m0 + r;
        if (d < N_NODES) {
            int2 nd = nodeoff[d];
            const int lo = nd.x, hi = nd.x + nd.y;   // padded len (x8)
            const float adh = a_dst[d * 4 + hd];

            float den = 0.f;
            float ax = 0.f, ay = 0.f, az = 0.f, aw = 0.f;

            if (half == 0) {   // self-loop on half 0
                float t = a_src[d * 4 + hd] + adh;
                t = t > 0.f ? t : 0.2f * t;
                float es = __expf(t);
                den = es;
                uint2 hu = ((const uint2*)(h_bf + (size_t)d * 64))[l32];
                float2 c01 = bf2f2(hu.x), c23 = bf2f2(hu.y);
                ax = c01.x * es; ay = c01.y * es;
                az = c23.x * es; aw = c23.y * es;
            }

            for (int base = lo; base < hi; base += 8) {
                int i0 = base + half;
                int s0 = csr_src[i0 + 0];
                int s1 = csr_src[i0 + 2];
                int s2 = csr_src[i0 + 4];
                int s3 = csr_src[i0 + 6];
                int g0 = s0 < 0 ? d : s0;
                int g1 = s1 < 0 ? d : s1;
                int g2 = s2 < 0 ? d : s2;
                int g3 = s3 < 0 ? d : s3;
                uint2 u0 = ((const uint2*)(h_bf + (size_t)g0 * 64))[l32];
                uint2 u1 = ((const uint2*)(h_bf + (size_t)g1 * 64))[l32];
                uint2 u2 = ((const uint2*)(h_bf + (size_t)g2 * 64))[l32];
                uint2 u3 = ((const uint2*)(h_bf + (size_t)g3 * 64))[l32];
                float a0 = a_src[g0 * 4 + hd];
                float a1 = a_src[g1 * 4 + hd];
                float a2 = a_src[g2 * 4 + hd];
                float a3 = a_src[g3 * 4 + hd];

                float t0 = a0 + adh; t0 = t0 > 0.f ? t0 : 0.2f * t0;
                float t1 = a1 + adh; t1 = t1 > 0.f ? t1 : 0.2f * t1;
                float t2 = a2 + adh; t2 = t2 > 0.f ? t2 : 0.2f * t2;
                float t3 = a3 + adh; t3 = t3 > 0.f ? t3 : 0.2f * t3;
                float e0 = s0 < 0 ? 0.f : __expf(t0);
                float e1 = s1 < 0 ? 0.f : __expf(t1);
                float e2 = s2 < 0 ? 0.f : __expf(t2);
                float e3 = s3 < 0 ? 0.f : __expf(t3);
                den += (e0 + e1) + (e2 + e3);

                float2 p, q;
                p = bf2f2(u0.x); q = bf2f2(u0.y);
                ax = fmaf(p.x, e0, ax); ay = fmaf(p.y, e0, ay);
                az = fmaf(q.x, e0, az); aw = fmaf(q.y, e0, aw);
                p = bf2f2(u1.x); q = bf2f2(u1.y);
                ax = fmaf(p.x, e1, ax); ay = fmaf(p.y, e1, ay);
                az = fmaf(q.x, e1, az); aw = fmaf(q.y, e1, aw);
                p = bf2f2(u2.x); q = bf2f2(u2.y);
                ax = fmaf(p.x, e2, ax); ay = fmaf(p.y, e2, ay);
                az = fmaf(q.x, e2, az); aw = fmaf(q.y, e2, aw);
                p = bf2f2(u3.x); q = bf2f2(u3.y);
                ax = fmaf(p.x, e3, ax); ay = fmaf(p.y, e3, ay);
                az = fmaf(q.x, e3, az); aw = fmaf(q.y, e3, aw);
            }

            den += __shfl_xor(den, 32);
            ax += __shfl_xor(ax, 32);
            ay += __shfl_xor(ay, 32);
            az += __shfl_xor(az, 32);
            aw += __shfl_xor(aw, 32);

            if (half == 0) {
                float inv = 1.f / (den + 1e-16f);
                half4v h4;
                h4[0] = (_Float16)elu_f(fmaf(ax, inv, bg.x));
                h4[1] = (_Float16)elu_f(fmaf(ay, inv, bg.y));
                h4[2] = (_Float16)elu_f(fmaf(az, inv, bg.z));
                h4[3] = (_Float16)elu_f(fmaf(aw, inv, bg.w));
                *(half4v*)&sx[r * 128 + l32 * 4] = h4;
            }
        } else if (half == 0) {
            *(half4v*)&sx[r * 128 + l32 * 4] = (half4v){0, 0, 0, 0};
        }
    }
    __syncthreads();

    // ---- MLP phase: 16 waves = 4 row-slabs x 4 N-groups ----
    const int lm = lane & 15, lq = lane >> 4;
    const int wr = wave >> 2, wn = wave & 3;
    const int wrow = wr * 16;

    // L1: E = X1 @ W_enc + b_enc   (N=64, wave wn owns nt=wn)
    {
        float4v acc = (float4v){0.f, 0.f, 0.f, 0.f};
#pragma unroll
        for (int kc = 0; kc < 4; kc++) {
            half8 a = *(const half8*)&sx[(wrow + lm) * 128 + kc * 32 + lq * 8];
            half8 b = *(const half8*)&swz[(kc * 4 + wn) * 512 + lane * 8];
            acc = __builtin_amdgcn_mfma_f32_16x16x32_f16(a, b, acc, 0, 0, 0);
        }
        float be = b_enc[wn * 16 + lm];
#pragma unroll
        for (int r = 0; r < 4; r++)
            se[(wrow + lq * 4 + r) * 64 + wn * 16 + lm] = (_Float16)(acc[r] + be);
    }
    __syncthreads();

    // L2: X2 = elu(E @ W_dec + b_dec) -> sx   (N=128, wave wn owns nt=2wn,2wn+1)
    {
        float4v acc[2];
        acc[0] = (float4v){0.f, 0.f, 0.f, 0.f};
        acc[1] = (float4v){0.f, 0.f, 0.f, 0.f};
#pragma unroll
        for (int kc = 0; kc < 2; kc++) {
            half8 a = *(const half8*)&se[(wrow + lm) * 64 + kc * 32 + lq * 8];
#pragma unroll
            for (int t = 0; t < 2; t++) {
                int nt = wn * 2 + t;
                half8 b = *(const half8*)&swz[8192 + (kc * 8 + nt) * 512 + lane * 8];
                acc[t] = __builtin_amdgcn_mfma_f32_16x16x32_f16(a, b, acc[t], 0, 0, 0);
            }
        }
#pragma unroll
        for (int t = 0; t < 2; t++) {
            int nt = wn * 2 + t;
            float bd = b_dec[nt * 16 + lm];
#pragma unroll
            for (int r = 0; r < 4; r++)
                sx[(wrow + lq * 4 + r) * 128 + nt * 16 + lm] =
                    (_Float16)elu_f(acc[t][r] + bd);
        }
    }
    __syncthreads();

    // L3: OUT = X2 @ W_out + b_out   (N=128)
    {
        float4v acc[2];
        acc[0] = (float4v){0.f, 0.f, 0.f, 0.f};
        acc[1] = (float4v){0.f, 0.f, 0.f, 0.f};
#pragma unroll
        for (int kc = 0; kc < 4; kc++) {
            half8 a = *(const half8*)&sx[(wrow + lm) * 128 + kc * 32 + lq * 8];
#pragma unroll
            for (int t = 0; t < 2; t++) {
                int nt = wn * 2 + t;
                half8 b = *(const half8*)&swz[16384 + (kc * 8 + nt) * 512 + lane * 8];
                acc[t] = __builtin_amdgcn_mfma_f32_16x16x32_f16(a, b, acc[t], 0, 0, 0);
            }
        }
#pragma unroll
        for (int t = 0; t < 2; t++) {
            int nt = wn * 2 + t;
            float bo = b_out[nt * 16 + lm];
#pragma unroll
            for (int r = 0; r < 4; r++) {
                int row = m0 + wrow + lq * 4 + r;
                if (row < N_NODES)
                    out[(size_t)row * 128 + nt * 16 + lm] = acc[t][r] + bo;
            }
        }
    }
}

extern "C" void kernel_launch(void* const* d_in, const int* in_sizes, int n_in,
                              void* d_out, int out_size, void* d_ws, size_t ws_size,
                              hipStream_t stream) {
    const float* x       = (const float*)d_in[0];
    const void*  e_raw   = d_in[1];
    const float* W_gat   = (const float*)d_in[2];
    const float* b_gat   = (const float*)d_in[3];
    const float* att_src = (const float*)d_in[4];
    const float* att_dst = (const float*)d_in[5];
    const float* W_enc   = (const float*)d_in[6];
    const float* b_enc   = (const float*)d_in[7];
    const float* W_dec   = (const float*)d_in[8];
    const float* b_dec   = (const float*)d_in[9];
    const float* W_out   = (const float*)d_in[10];
    const float* b_out   = (const float*)d_in[11];
    float* out = (float*)d_out;

    float* ws      = (float*)d_ws;
    float*   hreg  = ws;                       // 6,400,000 f
    unsigned* h_bf = (unsigned*)hreg;          // 3,200,000 u (50000 x 64)
    float* a_src   = hreg + 6400000;           // 200,000 f
    float* a_dst   = a_src + 200000;           // 200,000 f
    float* agg     = a_dst + 200000;           // region reused by ebuck
    uint2* ebuck   = (uint2*)agg;              // 196*8192*8B = 12.85 MB
    int*   csr_src = (int*)(agg + 6400000);    // 196*8192 = 1,605,632 i
    int2*  nodeoff = (int2*)(csr_src + NBUCK * CAP);  // 50,000 int2
    int*   flag    = (int*)(nodeoff + 50000);  // 1 i
    int*   bcursor = flag + 1;                 // 256 i
    _Float16* swz  = (_Float16*)(((uintptr_t)(bcursor + 256) + 15) & ~(uintptr_t)15); // 49152 f16

    k_pre<<<SWZ_BLOCKS + 1, 256, 0, stream>>>(
        e_raw, flag, W_enc, W_dec, W_out, W_gat, swz, bcursor);

    k_gatlin_bucket<<<NB_BUCKET_BLOCKS + GBLK, 256, 0, stream>>>(
        x, swz, att_src, att_dst, h_bf, a_src, a_dst,
        e_raw, flag, bcursor, ebuck);

    k_bfill<<<NBUCK, BFT, 0, stream>>>(ebuck, bcursor, nodeoff, csr_src);

    k_gather_mlp<<<GBLK, 1024, 0, stream>>>(
        nodeoff, csr_src, a_src, a_dst, h_bf, b_gat, swz,
        b_enc, b_dec, b_out, out);
}

// Round 5
// 187.041 us; speedup vs baseline: 1.0188x; 1.0188x over previous
//
#include <hip/hip_runtime.h>
#include <hip/hip_bf16.h>

#define N_NODES 50000
#define N_EDGES 800000
#define BM 64
#define NBUCK 196            // buckets of 256 nodes: d >> 8
#define CAP 8192             // per-bucket capacity (mean ~4096 real + <=1792 pad)
#define CHUNK 2048           // edges per block in bucket pass
#define NB_BUCKET_BLOCKS ((N_EDGES + CHUNK - 1) / CHUNK)   // 391
#define SWZ_BLOCKS 192                                     // 49152 halves
#define SWZ_G 32768          // W_gat offset in swz
#define BFT 1024             // k_bfill threads
#define GBLK ((N_NODES + BM - 1) / BM)                     // 782
#define SXP 136              // sx row pitch in f16 (272B: 16B-aligned, 2-way banks)
#define SEP 72               // se row pitch in f16 (144B: 16B-aligned, 2-way banks)

typedef _Float16 half4v __attribute__((ext_vector_type(4)));
typedef _Float16 half8 __attribute__((ext_vector_type(8)));
typedef float    float4v __attribute__((ext_vector_type(4)));

__device__ __forceinline__ float elu_f(float v) {
    return (v > 0.f) ? v : (__expf(v) - 1.f);
}

// pack two fp32 -> packed bf16x2 (RNE)
__device__ __forceinline__ unsigned f2bf2(float a, float b) {
    unsigned ua = __float_as_uint(a), ub = __float_as_uint(b);
    ua = (ua + 0x7FFFu + ((ua >> 16) & 1u)) >> 16;
    ub = (ub + 0x7FFFu + ((ub >> 16) & 1u)) >> 16;
    return ua | (ub << 16);
}
__device__ __forceinline__ float2 bf2f2(unsigned u) {
    float2 f;
    f.x = __uint_as_float(u << 16);
    f.y = __uint_as_float(u & 0xFFFF0000u);
    return f;
}

// ---------------- pre-pass: weight swizzle + {detect, bcursor zero} ------
// swz layout: [We 0..8192) N=64 | [Wd 8192..16384) N=128 | [Wo 16384..32768)
// N=128 | [Wg 32768..49152) N=128.
__global__ __launch_bounds__(256) void k_pre(const void* __restrict__ e_raw,
        int* __restrict__ flag,
        const float* __restrict__ We, const float* __restrict__ Wd,
        const float* __restrict__ Wo, const float* __restrict__ Wg,
        _Float16* __restrict__ swz, int* __restrict__ bcursor) {
    const int b = blockIdx.x;
    const int tid = threadIdx.x;
    if (b >= SWZ_BLOCKS) {
        __shared__ int nz;
        if (tid == 0) nz = 0;
        bcursor[tid] = 0;
        __syncthreads();
        int cnt = 0;
        const unsigned* er = (const unsigned*)e_raw;
        for (int i = tid; i < 2048; i += 256)
            if (er[2 * i + 1] != 0u) cnt = 1;
        if (cnt) atomicOr(&nz, 1);
        __syncthreads();
        if (tid == 0) *flag = (nz == 0) ? 1 : 0;   // 1 == int64 layout
        return;
    }
    int t = b * 256 + tid;
    const float* W; int base, N;
    if (t < 8192)       { W = We; base = 0;     N = 64;  }
    else if (t < 16384) { W = Wd; base = 8192;  N = 128; }
    else if (t < 32768) { W = Wo; base = 16384; N = 128; }
    else                { W = Wg; base = SWZ_G; N = 128; }
    int loc = t - base;
    int nnt = N >> 4;
    int frag = loc >> 9, r = loc & 511, lane = r >> 3, j = r & 7;
    int kc = frag / nnt, nt = frag - kc * nnt;
    int k = kc * 32 + ((lane >> 4) << 3) + j;
    int n = nt * 16 + (lane & 15);
    swz[t] = (_Float16)W[k * N + n];
}

// ---------------- fused K1: bucket blocks [0,391) + gat_lin blocks -------
__global__ __launch_bounds__(256) void k_gatlin_bucket(
        const float* __restrict__ x, const _Float16* __restrict__ swz,
        const float* __restrict__ att_s, const float* __restrict__ att_d,
        unsigned* __restrict__ h_bf, float* __restrict__ a_src,
        float* __restrict__ a_dst,
        const void* __restrict__ e_raw, const int* __restrict__ flag,
        int* __restrict__ bcursor, uint2* __restrict__ ebuck) {
    __shared__ __align__(16) char smem[64 * SXP * 2 + 64 * 132 * 4]; // 17408+33792
    const int tid = threadIdx.x;

    if (blockIdx.x < NB_BUCKET_BLOCKS) {
        // ---- bucket body: single-pass fixed-cap bucket sort ----
        int* lh    = (int*)smem;
        int* gbase = (int*)(smem + 1024);
        int* lcur  = (int*)(smem + 2048);
        const int base = blockIdx.x * CHUNK;
        const int is64 = *flag;
        const long long* e64 = (const long long*)e_raw;
        const int* e32 = (const int*)e_raw;

        lh[tid] = 0;
        __syncthreads();
#pragma unroll 4
        for (int j = 0; j < CHUNK / 256; j++) {
            int e = base + j * 256 + tid;
            if (e < N_EDGES) {
                int d = is64 ? (int)e64[N_EDGES + e] : e32[N_EDGES + e];
                atomicAdd(&lh[d >> 8], 1);
            }
        }
        __syncthreads();
        if (lh[tid]) gbase[tid] = atomicAdd(&bcursor[tid], lh[tid]);
        lcur[tid] = 0;
        __syncthreads();
#pragma unroll 4
        for (int j = 0; j < CHUNK / 256; j++) {
            int e = base + j * 256 + tid;
            if (e < N_EDGES) {
                int sN, d;
                if (is64) { sN = (int)e64[e]; d = (int)e64[N_EDGES + e]; }
                else      { sN = e32[e];      d = e32[N_EDGES + e]; }
                int bb = d >> 8;
                int idx = gbase[bb] + atomicAdd(&lcur[bb], 1);
                if (idx < CAP) {
                    uint2 pr; pr.x = (unsigned)sN; pr.y = (unsigned)d;
                    ebuck[bb * CAP + idx] = pr;
                }
            }
        }
        return;
    }

    // ---- gat_lin body: h(bf16) = x @ W_gat via MFMA; att head dots ----
    _Float16* sx = (_Float16*)smem;                    // 64 x SXP f16
    float*    sh = (float*)(smem + 64 * SXP * 2);      // 64 x 132 f32
    const int m0 = (blockIdx.x - NB_BUCKET_BLOCKS) * 64;

#pragma unroll
    for (int i = 0; i < 8; i++) {
        int idx = tid + i * 256;        // 2048 float4 slots (64 x 32)
        int r = idx >> 5, c4 = idx & 31;
        int row = m0 + r; if (row >= N_NODES) row = N_NODES - 1;
        float4 v = ((const float4*)(x + (size_t)row * 128))[c4];
        half4v h;
        h[0] = (_Float16)v.x; h[1] = (_Float16)v.y;
        h[2] = (_Float16)v.z; h[3] = (_Float16)v.w;
        *(half4v*)&sx[r * SXP + c4 * 4] = h;
    }
    __syncthreads();

    const int wave = tid >> 6, lane = tid & 63;
    const int lm = lane & 15, lq = lane >> 4;
    const int wrow = wave * 16;

    {
        float4v acc[8];
#pragma unroll
        for (int nt = 0; nt < 8; nt++) acc[nt] = (float4v){0.f, 0.f, 0.f, 0.f};
#pragma unroll
        for (int kc = 0; kc < 4; kc++) {
            half8 a = *(const half8*)&sx[(wrow + lm) * SXP + kc * 32 + lq * 8];
#pragma unroll
            for (int nt = 0; nt < 8; nt++) {
                half8 b = *(const half8*)&swz[SWZ_G + (kc * 8 + nt) * 512 + lane * 8];
                acc[nt] = __builtin_amdgcn_mfma_f32_16x16x32_f16(a, b, acc[nt], 0, 0, 0);
            }
        }
        // C/D layout: col = nt*16 + lm, row = lq*4 + r
#pragma unroll
        for (int nt = 0; nt < 8; nt++)
#pragma unroll
            for (int r = 0; r < 4; r++)
                sh[(wrow + lq * 4 + r) * 132 + nt * 16 + lm] = acc[nt][r];
    }
    __syncthreads();

    // epilogue: pack bf16 h + attention dots (8 rows x 4 cols per thread)
    const int c0 = (tid & 31) * 4;
    const int r0 = (tid >> 5) * 8;
    float4 as4 = *(const float4*)&att_s[c0];
    float4 ad4 = *(const float4*)&att_d[c0];
    const int head = c0 >> 5;

#pragma unroll
    for (int r = 0; r < 8; r++) {
        int row = m0 + r0 + r;
        bool ok = row < N_NODES;
        float4 hv = *(const float4*)&sh[(r0 + r) * 132 + c0];
        if (ok) {
            uint2 p;
            p.x = f2bf2(hv.x, hv.y);
            p.y = f2bf2(hv.z, hv.w);
            *(uint2*)&h_bf[(size_t)row * 64 + (c0 >> 1)] = p;
        }
        float vs = hv.x * as4.x + hv.y * as4.y + hv.z * as4.z + hv.w * as4.w;
        float vd = hv.x * ad4.x + hv.y * ad4.y + hv.z * ad4.z + hv.w * ad4.w;
#pragma unroll
        for (int o = 4; o >= 1; o >>= 1) {
            vs += __shfl_down(vs, o, 8);
            vd += __shfl_down(vd, o, 8);
        }
        if (ok && (tid & 7) == 0) {
            a_src[row * 4 + head] = vs;
            a_dst[row * 4 + head] = vd;
        }
    }
}

// per-bucket fine sort -> nodeoff(start, padded_len) + csr_src.
// Segments padded to multiples of 8 with sentinel -1 (no gather tail).
__global__ __launch_bounds__(BFT) void k_bfill(const uint2* __restrict__ ebuck,
        const int* __restrict__ bcursor, int2* __restrict__ nodeoff,
        int* __restrict__ csr_src) {
    __shared__ int lh[256];
    __shared__ int lexc[256];
    __shared__ int lcur[256];
    const int tid = threadIdx.x;
    const int b = blockIdx.x;
    const int lo = b * CAP;
    int cnt = bcursor[b]; if (cnt > CAP) cnt = CAP;
    const int hi = lo + cnt;
    const int n0 = b << 8;

    if (tid < 256) { lh[tid] = 0; lcur[tid] = 0; }
    __syncthreads();
    for (int i = lo + tid; i < hi; i += BFT)
        atomicAdd(&lh[ebuck[i].y & 255], 1);
    __syncthreads();

    int v = 0, p = 0;
    if (tid < 256) {
        v = lh[tid];
        p = (v + 7) & ~7;       // padded length
        lexc[tid] = p;
    }
    __syncthreads();
    for (int o = 1; o < 256; o <<= 1) {
        int u = (tid < 256 && tid >= o) ? lexc[tid - o] : 0;
        __syncthreads();
        if (tid < 256) lexc[tid] += u;
        __syncthreads();
    }
    if (tid < 256) {
        int s = lexc[tid] - p;   // exclusive padded start
        lexc[tid] = s;
        int node = n0 + tid;
        if (node < N_NODES) {
            int2 no;
            no.x = lo + s;
            int maxlen = CAP - s; if (maxlen < 0) maxlen = 0;
            no.y = p <= maxlen ? p : (maxlen & ~7);   // defensive clamp
            nodeoff[node] = no;
        }
    }
    __syncthreads();

    for (int i = lo + tid; i < hi; i += BFT) {
        uint2 pr = ebuck[i];
        int li = (int)(pr.y & 255);
        int pos = atomicAdd(&lcur[li], 1);
        int dst = lexc[li] + pos;
        if (dst < CAP) csr_src[lo + dst] = (int)pr.x;   // clamp: bucket-local
    }
    // sentinel pad fill (disjoint slots from the scatter above)
    if (tid < 256) {
        int base = lexc[tid];
        for (int j = v; j < p && base + j < CAP; j++) csr_src[lo + base + j] = -1;
    }
}

// ---------------- fused K3+K4: gather -> LDS -> 3-layer MFMA MLP ---------
// 1024 threads = 16 waves per 64-node tile. Gather: wave w owns nodes
// m0+4w..+3, writes x1 = elu(agg+b_gat) as f16 straight into sx.
// MLP: wave (wr=w>>2, wn=w&3) does row-slab wr (16 rows) x N-group wn.
__global__ __launch_bounds__(1024) void k_gather_mlp(
        const int2* __restrict__ nodeoff, const int* __restrict__ csr_src,
        const float* __restrict__ a_src, const float* __restrict__ a_dst,
        const unsigned* __restrict__ h_bf, const float* __restrict__ b_gat,
        const _Float16* __restrict__ swz, const float* __restrict__ b_enc,
        const float* __restrict__ b_dec, const float* __restrict__ b_out,
        float* __restrict__ out) {
    __shared__ _Float16 sx[64 * SXP];    // 17 KB: X1, then X2
    __shared__ _Float16 se[64 * SEP];    // 9 KB: E
    const int tid = threadIdx.x;
    const int wave = tid >> 6, lane = tid & 63;
    const int m0 = blockIdx.x * 64;
    const int half = lane >> 5;
    const int l32 = lane & 31;
    const int hd = l32 >> 3;
    const float4 bg = ((const float4*)b_gat)[l32];

    // ---- gather phase: 4 nodes per wave ----
    for (int k = 0; k < 4; k++) {
        const int r = wave * 4 + k;
        const int d = m0 + r;
        if (d < N_NODES) {
            int2 nd = nodeoff[d];
            const int lo = nd.x, hi = nd.x + nd.y;   // padded len (x8)
            const float adh = a_dst[d * 4 + hd];

            float den = 0.f;
            float ax = 0.f, ay = 0.f, az = 0.f, aw = 0.f;

            if (half == 0) {   // self-loop on half 0
                float t = a_src[d * 4 + hd] + adh;
                t = t > 0.f ? t : 0.2f * t;
                float es = __expf(t);
                den = es;
                uint2 hu = ((const uint2*)(h_bf + (size_t)d * 64))[l32];
                float2 c01 = bf2f2(hu.x), c23 = bf2f2(hu.y);
                ax = c01.x * es; ay = c01.y * es;
                az = c23.x * es; aw = c23.y * es;
            }

            for (int base = lo; base < hi; base += 8) {
                int i0 = base + half;
                int s0 = csr_src[i0 + 0];
                int s1 = csr_src[i0 + 2];
                int s2 = csr_src[i0 + 4];
                int s3 = csr_src[i0 + 6];
                int g0 = s0 < 0 ? d : s0;
                int g1 = s1 < 0 ? d : s1;
                int g2 = s2 < 0 ? d : s2;
                int g3 = s3 < 0 ? d : s3;
                uint2 u0 = ((const uint2*)(h_bf + (size_t)g0 * 64))[l32];
                uint2 u1 = ((const uint2*)(h_bf + (size_t)g1 * 64))[l32];
                uint2 u2 = ((const uint2*)(h_bf + (size_t)g2 * 64))[l32];
                uint2 u3 = ((const uint2*)(h_bf + (size_t)g3 * 64))[l32];
                float a0 = a_src[g0 * 4 + hd];
                float a1 = a_src[g1 * 4 + hd];
                float a2 = a_src[g2 * 4 + hd];
                float a3 = a_src[g3 * 4 + hd];

                float t0 = a0 + adh; t0 = t0 > 0.f ? t0 : 0.2f * t0;
                float t1 = a1 + adh; t1 = t1 > 0.f ? t1 : 0.2f * t1;
                float t2 = a2 + adh; t2 = t2 > 0.f ? t2 : 0.2f * t2;
                float t3 = a3 + adh; t3 = t3 > 0.f ? t3 : 0.2f * t3;
                float e0 = s0 < 0 ? 0.f : __expf(t0);
                float e1 = s1 < 0 ? 0.f : __expf(t1);
                float e2 = s2 < 0 ? 0.f : __expf(t2);
                float e3 = s3 < 0 ? 0.f : __expf(t3);
                den += (e0 + e1) + (e2 + e3);

                float2 p, q;
                p = bf2f2(u0.x); q = bf2f2(u0.y);
                ax = fmaf(p.x, e0, ax); ay = fmaf(p.y, e0, ay);
                az = fmaf(q.x, e0, az); aw = fmaf(q.y, e0, aw);
                p = bf2f2(u1.x); q = bf2f2(u1.y);
                ax = fmaf(p.x, e1, ax); ay = fmaf(p.y, e1, ay);
                az = fmaf(q.x, e1, az); aw = fmaf(q.y, e1, aw);
                p = bf2f2(u2.x); q = bf2f2(u2.y);
                ax = fmaf(p.x, e2, ax); ay = fmaf(p.y, e2, ay);
                az = fmaf(q.x, e2, az); aw = fmaf(q.y, e2, aw);
                p = bf2f2(u3.x); q = bf2f2(u3.y);
                ax = fmaf(p.x, e3, ax); ay = fmaf(p.y, e3, ay);
                az = fmaf(q.x, e3, az); aw = fmaf(q.y, e3, aw);
            }

            den += __shfl_xor(den, 32);
            ax += __shfl_xor(ax, 32);
            ay += __shfl_xor(ay, 32);
            az += __shfl_xor(az, 32);
            aw += __shfl_xor(aw, 32);

            if (half == 0) {
                float inv = 1.f / (den + 1e-16f);
                half4v h4;
                h4[0] = (_Float16)elu_f(fmaf(ax, inv, bg.x));
                h4[1] = (_Float16)elu_f(fmaf(ay, inv, bg.y));
                h4[2] = (_Float16)elu_f(fmaf(az, inv, bg.z));
                h4[3] = (_Float16)elu_f(fmaf(aw, inv, bg.w));
                *(half4v*)&sx[r * SXP + l32 * 4] = h4;
            }
        } else if (half == 0) {
            *(half4v*)&sx[r * SXP + l32 * 4] = (half4v){0, 0, 0, 0};
        }
    }
    __syncthreads();

    // ---- MLP phase: 16 waves = 4 row-slabs x 4 N-groups ----
    const int lm = lane & 15, lq = lane >> 4;
    const int wr = wave >> 2, wn = wave & 3;
    const int wrow = wr * 16;

    // L1: E = X1 @ W_enc + b_enc   (N=64, wave wn owns nt=wn)
    {
        float4v acc = (float4v){0.f, 0.f, 0.f, 0.f};
#pragma unroll
        for (int kc = 0; kc < 4; kc++) {
            half8 a = *(const half8*)&sx[(wrow + lm) * SXP + kc * 32 + lq * 8];
            half8 b = *(const half8*)&swz[(kc * 4 + wn) * 512 + lane * 8];
            acc = __builtin_amdgcn_mfma_f32_16x16x32_f16(a, b, acc, 0, 0, 0);
        }
        float be = b_enc[wn * 16 + lm];
#pragma unroll
        for (int r = 0; r < 4; r++)
            se[(wrow + lq * 4 + r) * SEP + wn * 16 + lm] = (_Float16)(acc[r] + be);
    }
    __syncthreads();

    // L2: X2 = elu(E @ W_dec + b_dec) -> sx   (N=128, wave wn owns nt=2wn,2wn+1)
    {
        float4v acc[2];
        acc[0] = (float4v){0.f, 0.f, 0.f, 0.f};
        acc[1] = (float4v){0.f, 0.f, 0.f, 0.f};
#pragma unroll
        for (int kc = 0; kc < 2; kc++) {
            half8 a = *(const half8*)&se[(wrow + lm) * SEP + kc * 32 + lq * 8];
#pragma unroll
            for (int t = 0; t < 2; t++) {
                int nt = wn * 2 + t;
                half8 b = *(const half8*)&swz[8192 + (kc * 8 + nt) * 512 + lane * 8];
                acc[t] = __builtin_amdgcn_mfma_f32_16x16x32_f16(a, b, acc[t], 0, 0, 0);
            }
        }
#pragma unroll
        for (int t = 0; t < 2; t++) {
            int nt = wn * 2 + t;
            float bd = b_dec[nt * 16 + lm];
#pragma unroll
            for (int r = 0; r < 4; r++)
                sx[(wrow + lq * 4 + r) * SXP + nt * 16 + lm] =
                    (_Float16)elu_f(acc[t][r] + bd);
        }
    }
    __syncthreads();

    // L3: OUT = X2 @ W_out + b_out   (N=128)
    {
        float4v acc[2];
        acc[0] = (float4v){0.f, 0.f, 0.f, 0.f};
        acc[1] = (float4v){0.f, 0.f, 0.f, 0.f};
#pragma unroll
        for (int kc = 0; kc < 4; kc++) {
            half8 a = *(const half8*)&sx[(wrow + lm) * SXP + kc * 32 + lq * 8];
#pragma unroll
            for (int t = 0; t < 2; t++) {
                int nt = wn * 2 + t;
                half8 b = *(const half8*)&swz[16384 + (kc * 8 + nt) * 512 + lane * 8];
                acc[t] = __builtin_amdgcn_mfma_f32_16x16x32_f16(a, b, acc[t], 0, 0, 0);
            }
        }
#pragma unroll
        for (int t = 0; t < 2; t++) {
            int nt = wn * 2 + t;
            float bo = b_out[nt * 16 + lm];
#pragma unroll
            for (int r = 0; r < 4; r++) {
                int row = m0 + wrow + lq * 4 + r;
                if (row < N_NODES)
                    out[(size_t)row * 128 + nt * 16 + lm] = acc[t][r] + bo;
            }
        }
    }
}

extern "C" void kernel_launch(void* const* d_in, const int* in_sizes, int n_in,
                              void* d_out, int out_size, void* d_ws, size_t ws_size,
                              hipStream_t stream) {
    const float* x       = (const float*)d_in[0];
    const void*  e_raw   = d_in[1];
    const float* W_gat   = (const float*)d_in[2];
    const float* b_gat   = (const float*)d_in[3];
    const float* att_src = (const float*)d_in[4];
    const float* att_dst = (const float*)d_in[5];
    const float* W_enc   = (const float*)d_in[6];
    const float* b_enc   = (const float*)d_in[7];
    const float* W_dec   = (const float*)d_in[8];
    const float* b_dec   = (const float*)d_in[9];
    const float* W_out   = (const float*)d_in[10];
    const float* b_out   = (const float*)d_in[11];
    float* out = (float*)d_out;

    float* ws      = (float*)d_ws;
    float*   hreg  = ws;                       // 6,400,000 f
    unsigned* h_bf = (unsigned*)hreg;          // 3,200,000 u (50000 x 64)
    float* a_src   = hreg + 6400000;           // 200,000 f
    float* a_dst   = a_src + 200000;           // 200,000 f
    float* agg     = a_dst + 200000;           // region reused by ebuck
    uint2* ebuck   = (uint2*)agg;              // 196*8192*8B = 12.85 MB
    int*   csr_src = (int*)(agg + 6400000);    // 196*8192 = 1,605,632 i
    int2*  nodeoff = (int2*)(csr_src + NBUCK * CAP);  // 50,000 int2
    int*   flag    = (int*)(nodeoff + 50000);  // 1 i
    int*   bcursor = flag + 1;                 // 256 i
    _Float16* swz  = (_Float16*)(((uintptr_t)(bcursor + 256) + 15) & ~(uintptr_t)15); // 49152 f16

    k_pre<<<SWZ_BLOCKS + 1, 256, 0, stream>>>(
        e_raw, flag, W_enc, W_dec, W_out, W_gat, swz, bcursor);

    k_gatlin_bucket<<<NB_BUCKET_BLOCKS + GBLK, 256, 0, stream>>>(
        x, swz, att_src, att_dst, h_bf, a_src, a_dst,
        e_raw, flag, bcursor, ebuck);

    k_bfill<<<NBUCK, BFT, 0, stream>>>(ebuck, bcursor, nodeoff, csr_src);

    k_gather_mlp<<<GBLK, 1024, 0, stream>>>(
        nodeoff, csr_src, a_src, a_dst, h_bf, b_gat, swz,
        b_enc, b_dec, b_out, out);
}

// Round 6
// 186.306 us; speedup vs baseline: 1.0228x; 1.0039x over previous
//
#include <hip/hip_runtime.h>
#include <hip/hip_bf16.h>

#define N_NODES 50000
#define N_EDGES 800000
#define BM 64
#define NBUCK 196            // buckets of 256 nodes: d >> 8
#define CAP 8192             // per-bucket capacity (mean ~4096 real + <=1792 pad)
#define CHUNK 2048           // edges per block in bucket pass
#define NB_BUCKET_BLOCKS ((N_EDGES + CHUNK - 1) / CHUNK)   // 391
#define SWZ_BLOCKS 192                                     // 49152 halves
#define SWZ_G 32768          // W_gat offset in swz
#define BFT 1024             // k_bfill threads
#define GBLK ((N_NODES + BM - 1) / BM)                     // 782
#define SXP 136              // sx row pitch f16 (272B: 16B-aligned, 2-way banks)
#define SEP 72               // se row pitch f16 (144B: 16B-aligned, 2-way banks)

typedef _Float16 half4v __attribute__((ext_vector_type(4)));
typedef _Float16 half8 __attribute__((ext_vector_type(8)));
typedef float    float4v __attribute__((ext_vector_type(4)));

__device__ __forceinline__ float elu_f(float v) {
    return (v > 0.f) ? v : (__expf(v) - 1.f);
}

// pack two fp32 -> packed bf16x2 (RNE)
__device__ __forceinline__ unsigned f2bf2(float a, float b) {
    unsigned ua = __float_as_uint(a), ub = __float_as_uint(b);
    ua = (ua + 0x7FFFu + ((ua >> 16) & 1u)) >> 16;
    ub = (ub + 0x7FFFu + ((ub >> 16) & 1u)) >> 16;
    return ua | (ub << 16);
}
__device__ __forceinline__ float2 bf2f2(unsigned u) {
    float2 f;
    f.x = __uint_as_float(u << 16);
    f.y = __uint_as_float(u & 0xFFFF0000u);
    return f;
}

// ---------------- pre-pass: weight swizzle + {detect, bcursor zero} ------
__global__ __launch_bounds__(256) void k_pre(const void* __restrict__ e_raw,
        int* __restrict__ flag,
        const float* __restrict__ We, const float* __restrict__ Wd,
        const float* __restrict__ Wo, const float* __restrict__ Wg,
        _Float16* __restrict__ swz, int* __restrict__ bcursor) {
    const int b = blockIdx.x;
    const int tid = threadIdx.x;
    if (b >= SWZ_BLOCKS) {
        __shared__ int nz;
        if (tid == 0) nz = 0;
        bcursor[tid] = 0;
        __syncthreads();
        int cnt = 0;
        const unsigned* er = (const unsigned*)e_raw;
        for (int i = tid; i < 2048; i += 256)
            if (er[2 * i + 1] != 0u) cnt = 1;
        if (cnt) atomicOr(&nz, 1);
        __syncthreads();
        if (tid == 0) *flag = (nz == 0) ? 1 : 0;   // 1 == int64 layout
        return;
    }
    int t = b * 256 + tid;
    const float* W; int base, N;
    if (t < 8192)       { W = We; base = 0;     N = 64;  }
    else if (t < 16384) { W = Wd; base = 8192;  N = 128; }
    else if (t < 32768) { W = Wo; base = 16384; N = 128; }
    else                { W = Wg; base = SWZ_G; N = 128; }
    int loc = t - base;
    int nnt = N >> 4;
    int frag = loc >> 9, r = loc & 511, lane = r >> 3, j = r & 7;
    int kc = frag / nnt, nt = frag - kc * nnt;
    int k = kc * 32 + ((lane >> 4) << 3) + j;
    int n = nt * 16 + (lane & 15);
    swz[t] = (_Float16)W[k * N + n];
}

// ---------------- fused K1: bucket blocks [0,391) + gat_lin blocks -------
__global__ __launch_bounds__(256) void k_gatlin_bucket(
        const float* __restrict__ x, const _Float16* __restrict__ swz,
        const float* __restrict__ att_s, const float* __restrict__ att_d,
        unsigned* __restrict__ h_bf, float* __restrict__ a_src,
        float* __restrict__ a_dst,
        const void* __restrict__ e_raw, const int* __restrict__ flag,
        int* __restrict__ bcursor, uint2* __restrict__ ebuck) {
    __shared__ __align__(16) char smem[64 * SXP * 2 + 64 * 132 * 4]; // 17408+33792
    const int tid = threadIdx.x;

    if (blockIdx.x < NB_BUCKET_BLOCKS) {
        // ---- bucket body: single-pass fixed-cap bucket sort ----
        int* lh    = (int*)smem;
        int* gbase = (int*)(smem + 1024);
        int* lcur  = (int*)(smem + 2048);
        const int base = blockIdx.x * CHUNK;
        const int is64 = *flag;
        const long long* e64 = (const long long*)e_raw;
        const int* e32 = (const int*)e_raw;

        lh[tid] = 0;
        __syncthreads();
#pragma unroll 4
        for (int j = 0; j < CHUNK / 256; j++) {
            int e = base + j * 256 + tid;
            if (e < N_EDGES) {
                int d = is64 ? (int)e64[N_EDGES + e] : e32[N_EDGES + e];
                atomicAdd(&lh[d >> 8], 1);
            }
        }
        __syncthreads();
        if (lh[tid]) gbase[tid] = atomicAdd(&bcursor[tid], lh[tid]);
        lcur[tid] = 0;
        __syncthreads();
#pragma unroll 4
        for (int j = 0; j < CHUNK / 256; j++) {
            int e = base + j * 256 + tid;
            if (e < N_EDGES) {
                int sN, d;
                if (is64) { sN = (int)e64[e]; d = (int)e64[N_EDGES + e]; }
                else      { sN = e32[e];      d = e32[N_EDGES + e]; }
                int bb = d >> 8;
                int idx = gbase[bb] + atomicAdd(&lcur[bb], 1);
                if (idx < CAP) {
                    uint2 pr; pr.x = (unsigned)sN; pr.y = (unsigned)d;
                    ebuck[bb * CAP + idx] = pr;
                }
            }
        }
        return;
    }

    // ---- gat_lin body: h(bf16) = x @ W_gat via MFMA; att head dots ----
    _Float16* sx = (_Float16*)smem;                    // 64 x SXP f16
    float*    sh = (float*)(smem + 64 * SXP * 2);      // 64 x 132 f32
    const int m0 = (blockIdx.x - NB_BUCKET_BLOCKS) * 64;

#pragma unroll
    for (int i = 0; i < 8; i++) {
        int idx = tid + i * 256;        // 2048 float4 slots (64 x 32)
        int r = idx >> 5, c4 = idx & 31;
        int row = m0 + r; if (row >= N_NODES) row = N_NODES - 1;
        float4 v = ((const float4*)(x + (size_t)row * 128))[c4];
        half4v h;
        h[0] = (_Float16)v.x; h[1] = (_Float16)v.y;
        h[2] = (_Float16)v.z; h[3] = (_Float16)v.w;
        *(half4v*)&sx[r * SXP + c4 * 4] = h;
    }
    __syncthreads();

    const int wave = tid >> 6, lane = tid & 63;
    const int lm = lane & 15, lq = lane >> 4;
    const int wrow = wave * 16;

    {
        float4v acc[8];
#pragma unroll
        for (int nt = 0; nt < 8; nt++) acc[nt] = (float4v){0.f, 0.f, 0.f, 0.f};
#pragma unroll
        for (int kc = 0; kc < 4; kc++) {
            half8 a = *(const half8*)&sx[(wrow + lm) * SXP + kc * 32 + lq * 8];
#pragma unroll
            for (int nt = 0; nt < 8; nt++) {
                half8 b = *(const half8*)&swz[SWZ_G + (kc * 8 + nt) * 512 + lane * 8];
                acc[nt] = __builtin_amdgcn_mfma_f32_16x16x32_f16(a, b, acc[nt], 0, 0, 0);
            }
        }
        // C/D layout: col = nt*16 + lm, row = lq*4 + r
#pragma unroll
        for (int nt = 0; nt < 8; nt++)
#pragma unroll
            for (int r = 0; r < 4; r++)
                sh[(wrow + lq * 4 + r) * 132 + nt * 16 + lm] = acc[nt][r];
    }
    __syncthreads();

    // epilogue: pack bf16 h + attention dots (8 rows x 4 cols per thread)
    const int c0 = (tid & 31) * 4;
    const int r0 = (tid >> 5) * 8;
    float4 as4 = *(const float4*)&att_s[c0];
    float4 ad4 = *(const float4*)&att_d[c0];
    const int head = c0 >> 5;

#pragma unroll
    for (int r = 0; r < 8; r++) {
        int row = m0 + r0 + r;
        bool ok = row < N_NODES;
        float4 hv = *(const float4*)&sh[(r0 + r) * 132 + c0];
        if (ok) {
            uint2 p;
            p.x = f2bf2(hv.x, hv.y);
            p.y = f2bf2(hv.z, hv.w);
            *(uint2*)&h_bf[(size_t)row * 64 + (c0 >> 1)] = p;
        }
        float vs = hv.x * as4.x + hv.y * as4.y + hv.z * as4.z + hv.w * as4.w;
        float vd = hv.x * ad4.x + hv.y * ad4.y + hv.z * ad4.z + hv.w * ad4.w;
#pragma unroll
        for (int o = 4; o >= 1; o >>= 1) {
            vs += __shfl_down(vs, o, 8);
            vd += __shfl_down(vd, o, 8);
        }
        if (ok && (tid & 7) == 0) {
            a_src[row * 4 + head] = vs;
            a_dst[row * 4 + head] = vd;
        }
    }
}

// per-bucket fine sort -> nodeoff(start, padded_len) + csr_src.
__global__ __launch_bounds__(BFT) void k_bfill(const uint2* __restrict__ ebuck,
        const int* __restrict__ bcursor, int2* __restrict__ nodeoff,
        int* __restrict__ csr_src) {
    __shared__ int lh[256];
    __shared__ int lexc[256];
    __shared__ int lcur[256];
    const int tid = threadIdx.x;
    const int b = blockIdx.x;
    const int lo = b * CAP;
    int cnt = bcursor[b]; if (cnt > CAP) cnt = CAP;
    const int hi = lo + cnt;
    const int n0 = b << 8;

    if (tid < 256) { lh[tid] = 0; lcur[tid] = 0; }
    __syncthreads();
    for (int i = lo + tid; i < hi; i += BFT)
        atomicAdd(&lh[ebuck[i].y & 255], 1);
    __syncthreads();

    int v = 0, p = 0;
    if (tid < 256) {
        v = lh[tid];
        p = (v + 7) & ~7;       // padded length
        lexc[tid] = p;
    }
    __syncthreads();
    for (int o = 1; o < 256; o <<= 1) {
        int u = (tid < 256 && tid >= o) ? lexc[tid - o] : 0;
        __syncthreads();
        if (tid < 256) lexc[tid] += u;
        __syncthreads();
    }
    if (tid < 256) {
        int s = lexc[tid] - p;   // exclusive padded start
        lexc[tid] = s;
        int node = n0 + tid;
        if (node < N_NODES) {
            int2 no;
            no.x = lo + s;
            int maxlen = CAP - s; if (maxlen < 0) maxlen = 0;
            no.y = p <= maxlen ? p : (maxlen & ~7);   // defensive clamp
            nodeoff[node] = no;
        }
    }
    __syncthreads();

    for (int i = lo + tid; i < hi; i += BFT) {
        uint2 pr = ebuck[i];
        int li = (int)(pr.y & 255);
        int pos = atomicAdd(&lcur[li], 1);
        int dst = lexc[li] + pos;
        if (dst < CAP) csr_src[lo + dst] = (int)pr.x;   // clamp: bucket-local
    }
    // sentinel pad fill (disjoint slots from the scatter above)
    if (tid < 256) {
        int base = lexc[tid];
        for (int j = v; j < p && base + j < CAP; j++) csr_src[lo + base + j] = -1;
    }
}

// ---------------- K3: CSR gather — 1 node/wave (50K waves), f16 out ------
// Epilogue applies softmax-norm + b_gat + elu and stores X1 as f16, so
// k_mlp stages with pure copies (no fp32 round-trip, no cvt).
__global__ __launch_bounds__(256) void k_gather(const int2* __restrict__ nodeoff,
        const int* __restrict__ csr_src, const float* __restrict__ a_src,
        const float* __restrict__ a_dst, const unsigned* __restrict__ h_bf,
        const float* __restrict__ b_gat, _Float16* __restrict__ x1) {
    int d = blockIdx.x * 4 + (threadIdx.x >> 6);
    if (d >= N_NODES) return;
    const int lane = threadIdx.x & 63;
    const int half = lane >> 5;
    const int l32 = lane & 31;
    const int hd = l32 >> 3;             // head of channels 4*l32..+3
    const uint2* hb = (const uint2*)h_bf;   // 32 uint2 per node row
    int2 nd = nodeoff[d];
    const int lo = nd.x, hi = nd.x + nd.y;   // padded len (x8)

    const float adh = a_dst[(unsigned)(d * 4 + hd)];

    float den = 0.f;
    float ax = 0.f, ay = 0.f, az = 0.f, aw = 0.f;

    if (half == 0) {   // self-loop on half 0
        float t = a_src[(unsigned)(d * 4 + hd)] + adh;
        t = t > 0.f ? t : 0.2f * t;
        float es = __expf(t);
        den = es;
        uint2 hu = hb[(unsigned)(d << 5) + l32];
        float2 c01 = bf2f2(hu.x), c23 = bf2f2(hu.y);
        ax = c01.x * es; ay = c01.y * es;
        az = c23.x * es; aw = c23.y * es;
    }

    for (int base = lo; base < hi; base += 8) {
        int i0 = base + half;
        int s0 = csr_src[i0 + 0];
        int s1 = csr_src[i0 + 2];
        int s2 = csr_src[i0 + 4];
        int s3 = csr_src[i0 + 6];
        // sentinel (-1) -> read own row (cache hit), weight forced to 0
        unsigned g0 = (unsigned)(s0 < 0 ? d : s0);
        unsigned g1 = (unsigned)(s1 < 0 ? d : s1);
        unsigned g2 = (unsigned)(s2 < 0 ? d : s2);
        unsigned g3 = (unsigned)(s3 < 0 ? d : s3);
        uint2 u0 = hb[(g0 << 5) + l32];
        uint2 u1 = hb[(g1 << 5) + l32];
        uint2 u2 = hb[(g2 << 5) + l32];
        uint2 u3 = hb[(g3 << 5) + l32];
        float a0 = a_src[g0 * 4 + hd];
        float a1 = a_src[g1 * 4 + hd];
        float a2 = a_src[g2 * 4 + hd];
        float a3 = a_src[g3 * 4 + hd];

        float t0 = a0 + adh; t0 = t0 > 0.f ? t0 : 0.2f * t0;
        float t1 = a1 + adh; t1 = t1 > 0.f ? t1 : 0.2f * t1;
        float t2 = a2 + adh; t2 = t2 > 0.f ? t2 : 0.2f * t2;
        float t3 = a3 + adh; t3 = t3 > 0.f ? t3 : 0.2f * t3;
        float e0 = s0 < 0 ? 0.f : __expf(t0);
        float e1 = s1 < 0 ? 0.f : __expf(t1);
        float e2 = s2 < 0 ? 0.f : __expf(t2);
        float e3 = s3 < 0 ? 0.f : __expf(t3);
        den += (e0 + e1) + (e2 + e3);

        float2 p, q;
        p = bf2f2(u0.x); q = bf2f2(u0.y);
        ax = fmaf(p.x, e0, ax); ay = fmaf(p.y, e0, ay);
        az = fmaf(q.x, e0, az); aw = fmaf(q.y, e0, aw);
        p = bf2f2(u1.x); q = bf2f2(u1.y);
        ax = fmaf(p.x, e1, ax); ay = fmaf(p.y, e1, ay);
        az = fmaf(q.x, e1, az); aw = fmaf(q.y, e1, aw);
        p = bf2f2(u2.x); q = bf2f2(u2.y);
        ax = fmaf(p.x, e2, ax); ay = fmaf(p.y, e2, ay);
        az = fmaf(q.x, e2, az); aw = fmaf(q.y, e2, aw);
        p = bf2f2(u3.x); q = bf2f2(u3.y);
        ax = fmaf(p.x, e3, ax); ay = fmaf(p.y, e3, ay);
        az = fmaf(q.x, e3, az); aw = fmaf(q.y, e3, aw);
    }

    // merge halves
    den += __shfl_xor(den, 32);
    ax += __shfl_xor(ax, 32);
    ay += __shfl_xor(ay, 32);
    az += __shfl_xor(az, 32);
    aw += __shfl_xor(aw, 32);

    if (half == 0) {
        float inv = 1.f / (den + 1e-16f);
        float4 bg = ((const float4*)b_gat)[l32];
        half4v h4;
        h4[0] = (_Float16)elu_f(fmaf(ax, inv, bg.x));
        h4[1] = (_Float16)elu_f(fmaf(ay, inv, bg.y));
        h4[2] = (_Float16)elu_f(fmaf(az, inv, bg.z));
        h4[3] = (_Float16)elu_f(fmaf(aw, inv, bg.w));
        *(half4v*)&x1[(size_t)d * 128 + l32 * 4] = h4;
    }
}

// ---------------- K4: fused MLP via MFMA f16 (f16 input, padded LDS) -----
__global__ __launch_bounds__(256) void k_mlp(const _Float16* __restrict__ x1,
        const _Float16* __restrict__ swz, const float* __restrict__ b_enc,
        const float* __restrict__ b_dec, const float* __restrict__ b_out,
        float* __restrict__ out) {
    __shared__ _Float16 sx[64 * SXP];          // 17 KB
    __shared__ _Float16 se[4 * 16 * SEP];      // 9 KB
    const int tid = threadIdx.x;
    const int m0 = blockIdx.x * 64;

    // stage X1 (already elu(agg+b_gat), f16) -> padded LDS, pure copies
#pragma unroll
    for (int i = 0; i < 4; i++) {
        int idx = tid + i * 256;        // 1024 uint4 slots (64 rows x 16)
        int r = idx >> 4, c = idx & 15;
        int row = m0 + r; if (row >= N_NODES) row = N_NODES - 1;
        uint4 v = ((const uint4*)(x1 + (size_t)row * 128))[c];
        *(uint4*)&sx[r * SXP + c * 8] = v;
    }
    __syncthreads();

    const int wave = tid >> 6, lane = tid & 63;
    const int lm = lane & 15, lq = lane >> 4;
    const int wrow = wave * 16;
    _Float16* eslab = &se[wave * 16 * SEP];

    // L1: E = X1 @ W_enc + b_enc
    {
        float4v acc[4];
#pragma unroll
        for (int nt = 0; nt < 4; nt++) acc[nt] = (float4v){0.f, 0.f, 0.f, 0.f};
#pragma unroll
        for (int kc = 0; kc < 4; kc++) {
            half8 a = *(const half8*)&sx[(wrow + lm) * SXP + kc * 32 + lq * 8];
#pragma unroll
            for (int nt = 0; nt < 4; nt++) {
                half8 b = *(const half8*)&swz[(kc * 4 + nt) * 512 + lane * 8];
                acc[nt] = __builtin_amdgcn_mfma_f32_16x16x32_f16(a, b, acc[nt], 0, 0, 0);
            }
        }
#pragma unroll
        for (int nt = 0; nt < 4; nt++) {
            float be = b_enc[nt * 16 + lm];
#pragma unroll
            for (int r = 0; r < 4; r++)
                eslab[(lq * 4 + r) * SEP + nt * 16 + lm] = (_Float16)(acc[nt][r] + be);
        }
    }

    // L2: X2 = elu(E @ W_dec + b_dec) -> sx slab
    {
        float4v acc[8];
#pragma unroll
        for (int nt = 0; nt < 8; nt++) acc[nt] = (float4v){0.f, 0.f, 0.f, 0.f};
#pragma unroll
        for (int kc = 0; kc < 2; kc++) {
            half8 a = *(const half8*)&eslab[lm * SEP + kc * 32 + lq * 8];
#pragma unroll
            for (int nt = 0; nt < 8; nt++) {
                half8 b = *(const half8*)&swz[8192 + (kc * 8 + nt) * 512 + lane * 8];
                acc[nt] = __builtin_amdgcn_mfma_f32_16x16x32_f16(a, b, acc[nt], 0, 0, 0);
            }
        }
#pragma unroll
        for (int nt = 0; nt < 8; nt++) {
            float bd = b_dec[nt * 16 + lm];
#pragma unroll
            for (int r = 0; r < 4; r++)
                sx[(wrow + lq * 4 + r) * SXP + nt * 16 + lm] =
                    (_Float16)elu_f(acc[nt][r] + bd);
        }
    }

    // L3: OUT = X2 @ W_out + b_out
    {
        float4v acc[8];
#pragma unroll
        for (int nt = 0; nt < 8; nt++) acc[nt] = (float4v){0.f, 0.f, 0.f, 0.f};
#pragma unroll
        for (int kc = 0; kc < 4; kc++) {
            half8 a = *(const half8*)&sx[(wrow + lm) * SXP + kc * 32 + lq * 8];
#pragma unroll
            for (int nt = 0; nt < 8; nt++) {
                half8 b = *(const half8*)&swz[16384 + (kc * 8 + nt) * 512 + lane * 8];
                acc[nt] = __builtin_amdgcn_mfma_f32_16x16x32_f16(a, b, acc[nt], 0, 0, 0);
            }
        }
#pragma unroll
        for (int nt = 0; nt < 8; nt++) {
            float bo = b_out[nt * 16 + lm];
#pragma unroll
            for (int r = 0; r < 4; r++) {
                int row = m0 + wrow + lq * 4 + r;
                if (row < N_NODES)
                    out[(size_t)row * 128 + nt * 16 + lm] = acc[nt][r] + bo;
            }
        }
    }
}

extern "C" void kernel_launch(void* const* d_in, const int* in_sizes, int n_in,
                              void* d_out, int out_size, void* d_ws, size_t ws_size,
                              hipStream_t stream) {
    const float* x       = (const float*)d_in[0];
    const void*  e_raw   = d_in[1];
    const float* W_gat   = (const float*)d_in[2];
    const float* b_gat   = (const float*)d_in[3];
    const float* att_src = (const float*)d_in[4];
    const float* att_dst = (const float*)d_in[5];
    const float* W_enc   = (const float*)d_in[6];
    const float* b_enc   = (const float*)d_in[7];
    const float* W_dec   = (const float*)d_in[8];
    const float* b_dec   = (const float*)d_in[9];
    const float* W_out   = (const float*)d_in[10];
    const float* b_out   = (const float*)d_in[11];
    float* out = (float*)d_out;

    float* ws      = (float*)d_ws;
    float*   hreg  = ws;                       // 6,400,000 f
    unsigned* h_bf = (unsigned*)hreg;          // 3,200,000 u (50000 x 64)
    float* a_src   = hreg + 6400000;           // 200,000 f
    float* a_dst   = a_src + 200000;           // 200,000 f
    float* agg     = a_dst + 200000;           // region reused: ebuck then x1
    uint2* ebuck   = (uint2*)agg;              // 196*8192*8B = 12.85 MB
    _Float16* x1   = (_Float16*)agg;           // 6.4M f16 = 12.8 MB (after bfill)
    int*   csr_src = (int*)(agg + 6400000);    // 196*8192 = 1,605,632 i
    int2*  nodeoff = (int2*)(csr_src + NBUCK * CAP);  // 50,000 int2
    int*   flag    = (int*)(nodeoff + 50000);  // 1 i
    int*   bcursor = flag + 1;                 // 256 i
    _Float16* swz  = (_Float16*)(((uintptr_t)(bcursor + 256) + 15) & ~(uintptr_t)15); // 49152 f16

    k_pre<<<SWZ_BLOCKS + 1, 256, 0, stream>>>(
        e_raw, flag, W_enc, W_dec, W_out, W_gat, swz, bcursor);

    k_gatlin_bucket<<<NB_BUCKET_BLOCKS + GBLK, 256, 0, stream>>>(
        x, swz, att_src, att_dst, h_bf, a_src, a_dst,
        e_raw, flag, bcursor, ebuck);

    k_bfill<<<NBUCK, BFT, 0, stream>>>(ebuck, bcursor, nodeoff, csr_src);

    k_gather<<<(N_NODES + 3) / 4, 256, 0, stream>>>(
        nodeoff, csr_src, a_src, a_dst, h_bf, b_gat, x1);

    k_mlp<<<GBLK, 256, 0, stream>>>(x1, swz, b_enc, b_dec, b_out, out);
}

// Round 7
// 177.391 us; speedup vs baseline: 1.0742x; 1.0503x over previous
//
#include <hip/hip_runtime.h>
#include <hip/hip_bf16.h>

#define N_NODES 50000
#define N_EDGES 800000
#define BM 64
#define NBUCK 196            // buckets of 256 nodes: d >> 8
#define CAP 8192             // csr per-bucket capacity (real ~4096 + pad <=1792)
#define CHUNK 2048           // edges per bucket-chunk block
#define NCHUNK ((N_EDGES + CHUNK - 1) / CHUNK)             // 391
#define SUBCAP 32            // per-(bucket,chunk) fixed slots (mean 10.4, 6.7 sigma)
#define DCAP 5120            // dense LDS staging pairs (bucket mean 4081, 16 sigma)
#define SWZ_BLOCKS 192                                     // 49152 halves
#define SWZ_G 32768          // W_gat offset in swz
#define GBLK ((N_NODES + BM - 1) / BM)                     // 782
#define SXP 136              // sx row pitch f16 (272B: 16B-aligned, 2-way banks)
#define SEP 72               // se row pitch f16 (144B: 16B-aligned, 2-way banks)
#define SMEM_BYTES (64 * SXP * 2 + 64 * 132 * 4)           // 51200

typedef _Float16 half4v __attribute__((ext_vector_type(4)));
typedef _Float16 half8 __attribute__((ext_vector_type(8)));
typedef float    float4v __attribute__((ext_vector_type(4)));

__device__ __forceinline__ float elu_f(float v) {
    return (v > 0.f) ? v : (__expf(v) - 1.f);
}

// pack two fp32 -> packed bf16x2 (RNE)
__device__ __forceinline__ unsigned f2bf2(float a, float b) {
    unsigned ua = __float_as_uint(a), ub = __float_as_uint(b);
    ua = (ua + 0x7FFFu + ((ua >> 16) & 1u)) >> 16;
    ub = (ub + 0x7FFFu + ((ub >> 16) & 1u)) >> 16;
    return ua | (ub << 16);
}
__device__ __forceinline__ float2 bf2f2(unsigned u) {
    float2 f;
    f.x = __uint_as_float(u << 16);
    f.y = __uint_as_float(u & 0xFFFF0000u);
    return f;
}

// ---------------- L1: weight swizzle [0,192) ∥ bucket-fixed [192,583) ----
// Bucket writes to fixed per-(bucket,chunk) slots: no global atomics, no
// flag/zero dependencies. Each bucket block self-detects the edge dtype.
__global__ __launch_bounds__(256) void k_pre_bucket(const void* __restrict__ e_raw,
        const float* __restrict__ We, const float* __restrict__ Wd,
        const float* __restrict__ Wo, const float* __restrict__ Wg,
        _Float16* __restrict__ swz, uint2* __restrict__ ebuck2,
        int* __restrict__ cnt) {
    const int b = blockIdx.x;
    const int tid = threadIdx.x;
    if (b >= SWZ_BLOCKS) {
        // ---- bucket chunk c ----
        __shared__ int lh[256];
        __shared__ int isl;
        const int c = b - SWZ_BLOCKS;
        const int base = c * CHUNK;
        const long long* e64 = (const long long*)e_raw;
        const int* e32 = (const int*)e_raw;
        if (tid == 0) {
            // int64 layout iff sampled high words are all zero
            const unsigned* er = (const unsigned*)e_raw;
            int nz = 0;
            for (int j = 0; j < 64; j++) nz |= (er[2 * (base + j) + 1] != 0u);
            isl = nz ? 0 : 1;
        }
        lh[tid] = 0;
        __syncthreads();
        const int is64 = isl;
#pragma unroll 4
        for (int j = 0; j < CHUNK / 256; j++) {
            int e = base + j * 256 + tid;
            if (e < N_EDGES) {
                int sN, d;
                if (is64) { sN = (int)e64[e]; d = (int)e64[N_EDGES + e]; }
                else      { sN = e32[e];      d = e32[N_EDGES + e]; }
                int bb = d >> 8;
                int pos = atomicAdd(&lh[bb], 1);
                if (pos < SUBCAP) {   // 6.7-sigma guard
                    uint2 pr; pr.x = (unsigned)sN; pr.y = (unsigned)d;
                    ebuck2[((size_t)bb * NCHUNK + c) * SUBCAP + pos] = pr;
                }
            }
        }
        __syncthreads();
        int v = lh[tid]; if (v > SUBCAP) v = SUBCAP;
        cnt[c * 256 + tid] = v;
        return;
    }
    // ---- weight swizzle ----
    int t = b * 256 + tid;
    const float* W; int base, N;
    if (t < 8192)       { W = We; base = 0;     N = 64;  }
    else if (t < 16384) { W = Wd; base = 8192;  N = 128; }
    else if (t < 32768) { W = Wo; base = 16384; N = 128; }
    else                { W = Wg; base = SWZ_G; N = 128; }
    int loc = t - base;
    int nnt = N >> 4;
    int frag = loc >> 9, r = loc & 511, lane = r >> 3, j = r & 7;
    int kc = frag / nnt, nt = frag - kc * nnt;
    int k = kc * 32 + ((lane >> 4) << 3) + j;
    int n = nt * 16 + (lane & 15);
    swz[t] = (_Float16)W[k * N + n];
}

// ---------------- L2: bfill' blocks [0,196) ∥ gat_lin blocks [196,978) ---
// bfill': compact fixed-slot ebuck2 -> dense LDS -> node-sorted csr_src
// (padded to x8 with sentinel -1). gat_lin: h = x @ W_gat + att dots.
__global__ __launch_bounds__(256) void k_lin_bfill(
        const float* __restrict__ x, const _Float16* __restrict__ swz,
        const float* __restrict__ att_s, const float* __restrict__ att_d,
        unsigned* __restrict__ h_bf, float* __restrict__ a_src,
        float* __restrict__ a_dst,
        const uint2* __restrict__ ebuck2, const int* __restrict__ cnt,
        int2* __restrict__ nodeoff, int* __restrict__ csr_src) {
    __shared__ __align__(16) char smem[SMEM_BYTES];
    const int tid = threadIdx.x;

    if (blockIdx.x < NBUCK) {
        // ---- bfill' for bucket bkt ----
        uint2* dense = (uint2*)smem;                     // DCAP*8 = 40960
        int*   coff  = (int*)(smem + 40960);             // 392*4  = 1568
        int*   sc    = (int*)(smem + 42528);             // 1024
        int*   lh    = (int*)(smem + 43552);             // 1024
        int*   lexc  = (int*)(smem + 44576);             // 1024
        int*   lcur  = (int*)(smem + 45600);             // 1024
        const int bkt = blockIdx.x;
        const int lo = bkt * CAP;
        const int n0 = bkt << 8;

        // A: chunk-count scan (391 values, two 256-wide rounds)
        int v0 = cnt[tid * 256 + bkt];                   // chunks 0..255
        sc[tid] = v0;
        __syncthreads();
        for (int o = 1; o < 256; o <<= 1) {
            int u = (tid >= o) ? sc[tid - o] : 0;
            __syncthreads();
            sc[tid] += u;
            __syncthreads();
        }
        coff[tid] = sc[tid] - v0;
        int total0 = sc[255];
        __syncthreads();
        int c2 = tid + 256;
        int v1 = (c2 < NCHUNK) ? cnt[c2 * 256 + bkt] : 0;
        sc[tid] = v1;
        __syncthreads();
        for (int o = 1; o < 256; o <<= 1) {
            int u = (tid >= o) ? sc[tid - o] : 0;
            __syncthreads();
            sc[tid] += u;
            __syncthreads();
        }
        if (c2 < NCHUNK) coff[c2] = total0 + sc[tid] - v1;
        int cntb = total0 + sc[255];
        if (cntb > DCAP) cntb = DCAP;
        if (tid == 0) coff[NCHUNK] = cntb;
        __syncthreads();

        // B: compact to dense LDS (8 threads per chunk, 32 chunks in flight)
        {
            int cg = tid >> 3, j = tid & 7;
            for (int c = cg; c < NCHUNK; c += 32) {
                int off = coff[c];
                int n = coff[c + 1] - off;
                const uint2* src = &ebuck2[((size_t)bkt * NCHUNK + c) * SUBCAP];
                for (int e = j; e < n; e += 8)
                    if (off + e < DCAP) dense[off + e] = src[e];
            }
        }
        __syncthreads();

        // C: node histogram from LDS
        lh[tid] = 0;
        lcur[tid] = 0;
        __syncthreads();
        for (int i = tid; i < cntb; i += 256)
            atomicAdd(&lh[dense[i].y & 255], 1);
        __syncthreads();

        // D: padded (x8) exclusive scan -> nodeoff
        int v = lh[tid];
        int p = (v + 7) & ~7;
        lexc[tid] = p;
        __syncthreads();
        for (int o = 1; o < 256; o <<= 1) {
            int u = (tid >= o) ? lexc[tid - o] : 0;
            __syncthreads();
            lexc[tid] += u;
            __syncthreads();
        }
        {
            int s = lexc[tid] - p;   // exclusive padded start
            lexc[tid] = s;
            int node = n0 + tid;
            if (node < N_NODES) {
                int2 no;
                no.x = lo + s;
                int maxlen = CAP - s; if (maxlen < 0) maxlen = 0;
                no.y = p <= maxlen ? p : (maxlen & ~7);
                nodeoff[node] = no;
            }
        }
        __syncthreads();

        // E: scatter + F: sentinel pad
        for (int i = tid; i < cntb; i += 256) {
            uint2 pr = dense[i];
            int li = (int)(pr.y & 255);
            int pos = atomicAdd(&lcur[li], 1);
            int dst = lexc[li] + pos;
            if (dst < CAP) csr_src[lo + dst] = (int)pr.x;
        }
        {
            int base2 = lexc[tid];
            for (int j = v; j < p && base2 + j < CAP; j++)
                csr_src[lo + base2 + j] = -1;
        }
        return;
    }

    // ---- gat_lin body: h(bf16) = x @ W_gat via MFMA; att head dots ----
    _Float16* sx = (_Float16*)smem;                    // 64 x SXP f16
    float*    sh = (float*)(smem + 64 * SXP * 2);      // 64 x 132 f32
    const int m0 = (blockIdx.x - NBUCK) * 64;

#pragma unroll
    for (int i = 0; i < 8; i++) {
        int idx = tid + i * 256;        // 2048 float4 slots (64 x 32)
        int r = idx >> 5, c4 = idx & 31;
        int row = m0 + r; if (row >= N_NODES) row = N_NODES - 1;
        float4 v = ((const float4*)(x + (size_t)row * 128))[c4];
        half4v h;
        h[0] = (_Float16)v.x; h[1] = (_Float16)v.y;
        h[2] = (_Float16)v.z; h[3] = (_Float16)v.w;
        *(half4v*)&sx[r * SXP + c4 * 4] = h;
    }
    __syncthreads();

    const int wave = tid >> 6, lane = tid & 63;
    const int lm = lane & 15, lq = lane >> 4;
    const int wrow = wave * 16;

    {
        float4v acc[8];
#pragma unroll
        for (int nt = 0; nt < 8; nt++) acc[nt] = (float4v){0.f, 0.f, 0.f, 0.f};
#pragma unroll
        for (int kc = 0; kc < 4; kc++) {
            half8 a = *(const half8*)&sx[(wrow + lm) * SXP + kc * 32 + lq * 8];
#pragma unroll
            for (int nt = 0; nt < 8; nt++) {
                half8 b = *(const half8*)&swz[SWZ_G + (kc * 8 + nt) * 512 + lane * 8];
                acc[nt] = __builtin_amdgcn_mfma_f32_16x16x32_f16(a, b, acc[nt], 0, 0, 0);
            }
        }
        // C/D layout: col = nt*16 + lm, row = lq*4 + r
#pragma unroll
        for (int nt = 0; nt < 8; nt++)
#pragma unroll
            for (int r = 0; r < 4; r++)
                sh[(wrow + lq * 4 + r) * 132 + nt * 16 + lm] = acc[nt][r];
    }
    __syncthreads();

    // epilogue: pack bf16 h + attention dots (8 rows x 4 cols per thread)
    const int c0 = (tid & 31) * 4;
    const int r0 = (tid >> 5) * 8;
    float4 as4 = *(const float4*)&att_s[c0];
    float4 ad4 = *(const float4*)&att_d[c0];
    const int head = c0 >> 5;

#pragma unroll
    for (int r = 0; r < 8; r++) {
        int row = m0 + r0 + r;
        bool ok = row < N_NODES;
        float4 hv = *(const float4*)&sh[(r0 + r) * 132 + c0];
        if (ok) {
            uint2 p;
            p.x = f2bf2(hv.x, hv.y);
            p.y = f2bf2(hv.z, hv.w);
            *(uint2*)&h_bf[(size_t)row * 64 + (c0 >> 1)] = p;
        }
        float vs = hv.x * as4.x + hv.y * as4.y + hv.z * as4.z + hv.w * as4.w;
        float vd = hv.x * ad4.x + hv.y * ad4.y + hv.z * ad4.z + hv.w * ad4.w;
#pragma unroll
        for (int o = 4; o >= 1; o >>= 1) {
            vs += __shfl_down(vs, o, 8);
            vd += __shfl_down(vd, o, 8);
        }
        if (ok && (tid & 7) == 0) {
            a_src[row * 4 + head] = vs;
            a_dst[row * 4 + head] = vd;
        }
    }
}

// ---------------- K3: CSR gather — 1 node/wave, f16 x1 out ---------------
__global__ __launch_bounds__(256) void k_gather(const int2* __restrict__ nodeoff,
        const int* __restrict__ csr_src, const float* __restrict__ a_src,
        const float* __restrict__ a_dst, const unsigned* __restrict__ h_bf,
        const float* __restrict__ b_gat, _Float16* __restrict__ x1) {
    int d = blockIdx.x * 4 + (threadIdx.x >> 6);
    if (d >= N_NODES) return;
    const int lane = threadIdx.x & 63;
    const int half = lane >> 5;
    const int l32 = lane & 31;
    const int hd = l32 >> 3;             // head of channels 4*l32..+3
    const uint2* hb = (const uint2*)h_bf;   // 32 uint2 per node row
    int2 nd = nodeoff[d];
    const int lo = nd.x, hi = nd.x + nd.y;   // padded len (x8)

    const float adh = a_dst[(unsigned)(d * 4 + hd)];

    float den = 0.f;
    float ax = 0.f, ay = 0.f, az = 0.f, aw = 0.f;

    if (half == 0) {   // self-loop on half 0
        float t = a_src[(unsigned)(d * 4 + hd)] + adh;
        t = t > 0.f ? t : 0.2f * t;
        float es = __expf(t);
        den = es;
        uint2 hu = hb[(unsigned)(d << 5) + l32];
        float2 c01 = bf2f2(hu.x), c23 = bf2f2(hu.y);
        ax = c01.x * es; ay = c01.y * es;
        az = c23.x * es; aw = c23.y * es;
    }

    for (int base = lo; base < hi; base += 8) {
        int i0 = base + half;
        int s0 = csr_src[i0 + 0];
        int s1 = csr_src[i0 + 2];
        int s2 = csr_src[i0 + 4];
        int s3 = csr_src[i0 + 6];
        unsigned g0 = (unsigned)(s0 < 0 ? d : s0);
        unsigned g1 = (unsigned)(s1 < 0 ? d : s1);
        unsigned g2 = (unsigned)(s2 < 0 ? d : s2);
        unsigned g3 = (unsigned)(s3 < 0 ? d : s3);
        uint2 u0 = hb[(g0 << 5) + l32];
        uint2 u1 = hb[(g1 << 5) + l32];
        uint2 u2 = hb[(g2 << 5) + l32];
        uint2 u3 = hb[(g3 << 5) + l32];
        float a0 = a_src[g0 * 4 + hd];
        float a1 = a_src[g1 * 4 + hd];
        float a2 = a_src[g2 * 4 + hd];
        float a3 = a_src[g3 * 4 + hd];

        float t0 = a0 + adh; t0 = t0 > 0.f ? t0 : 0.2f * t0;
        float t1 = a1 + adh; t1 = t1 > 0.f ? t1 : 0.2f * t1;
        float t2 = a2 + adh; t2 = t2 > 0.f ? t2 : 0.2f * t2;
        float t3 = a3 + adh; t3 = t3 > 0.f ? t3 : 0.2f * t3;
        float e0 = s0 < 0 ? 0.f : __expf(t0);
        float e1 = s1 < 0 ? 0.f : __expf(t1);
        float e2 = s2 < 0 ? 0.f : __expf(t2);
        float e3 = s3 < 0 ? 0.f : __expf(t3);
        den += (e0 + e1) + (e2 + e3);

        float2 p, q;
        p = bf2f2(u0.x); q = bf2f2(u0.y);
        ax = fmaf(p.x, e0, ax); ay = fmaf(p.y, e0, ay);
        az = fmaf(q.x, e0, az); aw = fmaf(q.y, e0, aw);
        p = bf2f2(u1.x); q = bf2f2(u1.y);
        ax = fmaf(p.x, e1, ax); ay = fmaf(p.y, e1, ay);
        az = fmaf(q.x, e1, az); aw = fmaf(q.y, e1, aw);
        p = bf2f2(u2.x); q = bf2f2(u2.y);
        ax = fmaf(p.x, e2, ax); ay = fmaf(p.y, e2, ay);
        az = fmaf(q.x, e2, az); aw = fmaf(q.y, e2, aw);
        p = bf2f2(u3.x); q = bf2f2(u3.y);
        ax = fmaf(p.x, e3, ax); ay = fmaf(p.y, e3, ay);
        az = fmaf(q.x, e3, az); aw = fmaf(q.y, e3, aw);
    }

    // merge halves
    den += __shfl_xor(den, 32);
    ax += __shfl_xor(ax, 32);
    ay += __shfl_xor(ay, 32);
    az += __shfl_xor(az, 32);
    aw += __shfl_xor(aw, 32);

    if (half == 0) {
        float inv = 1.f / (den + 1e-16f);
        float4 bg = ((const float4*)b_gat)[l32];
        half4v h4;
        h4[0] = (_Float16)elu_f(fmaf(ax, inv, bg.x));
        h4[1] = (_Float16)elu_f(fmaf(ay, inv, bg.y));
        h4[2] = (_Float16)elu_f(fmaf(az, inv, bg.z));
        h4[3] = (_Float16)elu_f(fmaf(aw, inv, bg.w));
        *(half4v*)&x1[(size_t)d * 128 + l32 * 4] = h4;
    }
}

// ---------------- K4: fused MLP via MFMA f16 (f16 input, padded LDS) -----
__global__ __launch_bounds__(256) void k_mlp(const _Float16* __restrict__ x1,
        const _Float16* __restrict__ swz, const float* __restrict__ b_enc,
        const float* __restrict__ b_dec, const float* __restrict__ b_out,
        float* __restrict__ out) {
    __shared__ _Float16 sx[64 * SXP];          // 17 KB
    __shared__ _Float16 se[4 * 16 * SEP];      // 9 KB
    const int tid = threadIdx.x;
    const int m0 = blockIdx.x * 64;

    // stage X1 (already elu(agg+b_gat), f16) -> padded LDS, pure copies
#pragma unroll
    for (int i = 0; i < 4; i++) {
        int idx = tid + i * 256;        // 1024 uint4 slots (64 rows x 16)
        int r = idx >> 4, c = idx & 15;
        int row = m0 + r; if (row >= N_NODES) row = N_NODES - 1;
        uint4 v = ((const uint4*)(x1 + (size_t)row * 128))[c];
        *(uint4*)&sx[r * SXP + c * 8] = v;
    }
    __syncthreads();

    const int wave = tid >> 6, lane = tid & 63;
    const int lm = lane & 15, lq = lane >> 4;
    const int wrow = wave * 16;
    _Float16* eslab = &se[wave * 16 * SEP];

    // L1: E = X1 @ W_enc + b_enc
    {
        float4v acc[4];
#pragma unroll
        for (int nt = 0; nt < 4; nt++) acc[nt] = (float4v){0.f, 0.f, 0.f, 0.f};
#pragma unroll
        for (int kc = 0; kc < 4; kc++) {
            half8 a = *(const half8*)&sx[(wrow + lm) * SXP + kc * 32 + lq * 8];
#pragma unroll
            for (int nt = 0; nt < 4; nt++) {
                half8 b = *(const half8*)&swz[(kc * 4 + nt) * 512 + lane * 8];
                acc[nt] = __builtin_amdgcn_mfma_f32_16x16x32_f16(a, b, acc[nt], 0, 0, 0);
            }
        }
#pragma unroll
        for (int nt = 0; nt < 4; nt++) {
            float be = b_enc[nt * 16 + lm];
#pragma unroll
            for (int r = 0; r < 4; r++)
                eslab[(lq * 4 + r) * SEP + nt * 16 + lm] = (_Float16)(acc[nt][r] + be);
        }
    }

    // L2: X2 = elu(E @ W_dec + b_dec) -> sx slab
    {
        float4v acc[8];
#pragma unroll
        for (int nt = 0; nt < 8; nt++) acc[nt] = (float4v){0.f, 0.f, 0.f, 0.f};
#pragma unroll
        for (int kc = 0; kc < 2; kc++) {
            half8 a = *(const half8*)&eslab[lm * SEP + kc * 32 + lq * 8];
#pragma unroll
            for (int nt = 0; nt < 8; nt++) {
                half8 b = *(const half8*)&swz[8192 + (kc * 8 + nt) * 512 + lane * 8];
                acc[nt] = __builtin_amdgcn_mfma_f32_16x16x32_f16(a, b, acc[nt], 0, 0, 0);
            }
        }
#pragma unroll
        for (int nt = 0; nt < 8; nt++) {
            float bd = b_dec[nt * 16 + lm];
#pragma unroll
            for (int r = 0; r < 4; r++)
                sx[(wrow + lq * 4 + r) * SXP + nt * 16 + lm] =
                    (_Float16)elu_f(acc[nt][r] + bd);
        }
    }

    // L3: OUT = X2 @ W_out + b_out
    {
        float4v acc[8];
#pragma unroll
        for (int nt = 0; nt < 8; nt++) acc[nt] = (float4v){0.f, 0.f, 0.f, 0.f};
#pragma unroll
        for (int kc = 0; kc < 4; kc++) {
            half8 a = *(const half8*)&sx[(wrow + lm) * SXP + kc * 32 + lq * 8];
#pragma unroll
            for (int nt = 0; nt < 8; nt++) {
                half8 b = *(const half8*)&swz[16384 + (kc * 8 + nt) * 512 + lane * 8];
                acc[nt] = __builtin_amdgcn_mfma_f32_16x16x32_f16(a, b, acc[nt], 0, 0, 0);
            }
        }
#pragma unroll
        for (int nt = 0; nt < 8; nt++) {
            float bo = b_out[nt * 16 + lm];
#pragma unroll
            for (int r = 0; r < 4; r++) {
                int row = m0 + wrow + lq * 4 + r;
                if (row < N_NODES)
                    out[(size_t)row * 128 + nt * 16 + lm] = acc[nt][r] + bo;
            }
        }
    }
}

extern "C" void kernel_launch(void* const* d_in, const int* in_sizes, int n_in,
                              void* d_out, int out_size, void* d_ws, size_t ws_size,
                              hipStream_t stream) {
    const float* x       = (const float*)d_in[0];
    const void*  e_raw   = d_in[1];
    const float* W_gat   = (const float*)d_in[2];
    const float* b_gat   = (const float*)d_in[3];
    const float* att_src = (const float*)d_in[4];
    const float* att_dst = (const float*)d_in[5];
    const float* W_enc   = (const float*)d_in[6];
    const float* b_enc   = (const float*)d_in[7];
    const float* W_dec   = (const float*)d_in[8];
    const float* b_dec   = (const float*)d_in[9];
    const float* W_out   = (const float*)d_in[10];
    const float* b_out   = (const float*)d_in[11];
    float* out = (float*)d_out;

    float* ws      = (float*)d_ws;
    unsigned* h_bf = (unsigned*)ws;            // 3,200,000 u (50000 x 64)
    float* a_src   = ws + 6400000;             // 200,000 f
    float* a_dst   = a_src + 200000;           // 200,000 f
    float* agg     = a_dst + 200000;           // 6.4M-float region, reused:
    uint2* ebuck2  = (uint2*)agg;              //   196*391*32*8B = 19.6 MB
    _Float16* x1   = (_Float16*)agg;           //   12.8 MB (after bfill' done)
    int*   csr_src = (int*)(agg + 6400000);    // 196*8192 = 1,605,632 i
    int*   cnt     = csr_src + NBUCK * CAP;    // 391*256 = 100,096 i
    int2*  nodeoff = (int2*)(cnt + NCHUNK * 256);     // 50,000 int2
    _Float16* swz  = (_Float16*)(((uintptr_t)(nodeoff + 50000) + 15) & ~(uintptr_t)15);

    k_pre_bucket<<<SWZ_BLOCKS + NCHUNK, 256, 0, stream>>>(
        e_raw, W_enc, W_dec, W_out, W_gat, swz, ebuck2, cnt);

    k_lin_bfill<<<NBUCK + GBLK, 256, 0, stream>>>(
        x, swz, att_src, att_dst, h_bf, a_src, a_dst,
        ebuck2, cnt, nodeoff, csr_src);

    k_gather<<<(N_NODES + 3) / 4, 256, 0, stream>>>(
        nodeoff, csr_src, a_src, a_dst, h_bf, b_gat, x1);

    k_mlp<<<GBLK, 256, 0, stream>>>(x1, swz, b_enc, b_dec, b_out, out);
}